// Round 13
// baseline (79.484 us; speedup 1.0000x reference)
//
#include <hip/hip_runtime.h>
#include <stdint.h>

// ImportanceSparsification: per-batch top-k (k = 0.2*S*T) of 1/(cost+1e-8),
// out = (source, target, cost*mask). Exact selection with jax top_k
// tie-break (lowest flat index among equal importance values).
//
// R12 -> R13: same as R12 (phase-split histgather: loads -> bins -> NT
// stores -> rare-path atomics; NT copy role) but the nontemporal builtins
// go through clang ext_vector_type(4) pointers (HIP_vector_type<float,4>*
// is rejected by __builtin_nontemporal_*).

static constexpr int CAP   = 32768;   // per-batch candidate cap (global)
static constexpr int LCAP  = 256;     // per-block candidate staging (LDS)
static constexpr int LDSCV = 12288;   // solve: LDS-staged candidate values
static constexpr int TIECAP = 2048;   // solve: LDS tie / slow-path hist
static constexpr int HBINS = 512;     // slow-path linear cost bins
static constexpr int NT    = 512;     // solve block size
static constexpr int NW    = NT / 64; // waves in solve block
static constexpr uint32_t SPEC_LO = 100;  // speculative window (bins of 512)
static constexpr uint32_t SPEC_HI = 104;
static constexpr float EPSF = 1e-8f;

typedef float f32x4 __attribute__((ext_vector_type(4)));

__device__ __forceinline__ float4 ntload4(const float4* p) {
    f32x4 r = __builtin_nontemporal_load(reinterpret_cast<const f32x4*>(p));
    float4 v; v.x = r.x; v.y = r.y; v.z = r.z; v.w = r.w;
    return v;
}
__device__ __forceinline__ void ntstore4(const float4& v, float4* p) {
    f32x4 t; t.x = v.x; t.y = v.y; t.z = v.z; t.w = v.w;
    __builtin_nontemporal_store(t, reinterpret_cast<f32x4*>(p));
}

__device__ __forceinline__ uint32_t impBits(float c) {
    // IEEE-correct f32 ops (no fast-math) -> bit-exact vs numpy reference
    return __float_as_uint(1.0f / (c + EPSF));
}

__device__ __forceinline__ uint32_t costBin(float x) {
    uint32_t bi = (uint32_t)(x * (float)HBINS);  // x in [0,1)
    return bi > (HBINS - 1) ? (HBINS - 1) : bi;
}

// meta per batch (16 u32):
// [4]=candcnt [8]=below [9..13]=win[5] [15]=stage_overflow

// ---- pass 0: zero meta ----
__global__ __launch_bounds__(256) void init_kernel(
    uint32_t* __restrict__ meta, int B) {
    const int i = blockIdx.x * 256 + threadIdx.x;
    if (i < B * 16) meta[i] = 0u;
}

// ---- pass 1: stream phase (loads -> bins -> NT stores), then rare-path
//      candidate staging; copy-role blocks move src/tgt with NT ops ----
__global__ __launch_bounds__(256) void histgather_kernel(
    const float4* __restrict__ cost4, const float4* __restrict__ src4,
    const float4* __restrict__ tgt4, float4* __restrict__ out4,
    float4* __restrict__ outc4, uint32_t* __restrict__ meta,
    uint32_t* __restrict__ candv, uint32_t* __restrict__ candi,
    int n4, int nHist, int s4) {
    __shared__ uint32_t l_cv[LCAP];
    __shared__ uint32_t l_ci[LCAP];
    __shared__ uint32_t lh_win[5];
    __shared__ uint32_t l_below[4];
    __shared__ uint32_t l_cnt, l_base;
    const int bid = blockIdx.x;
    const int tid = threadIdx.x;
    if (bid >= nHist) {
        // copy role: out[0:s4) = src, out[s4:s4+t4) = tgt; 1024 float4/block
        const int i0 = (bid - nHist) * 1024;
        const int ia = i0 + 0 * 256 + tid;
        const int ib = i0 + 1 * 256 + tid;
        const int ic = i0 + 2 * 256 + tid;
        const int id = i0 + 3 * 256 + tid;
        float4 ca = (ia < s4) ? ntload4(&src4[ia]) : ntload4(&tgt4[ia - s4]);
        float4 cb = (ib < s4) ? ntload4(&src4[ib]) : ntload4(&tgt4[ib - s4]);
        float4 cc = (ic < s4) ? ntload4(&src4[ic]) : ntload4(&tgt4[ic - s4]);
        float4 cd = (id < s4) ? ntload4(&src4[id]) : ntload4(&tgt4[id - s4]);
        ntstore4(ca, &out4[ia]);
        ntstore4(cb, &out4[ib]);
        ntstore4(cc, &out4[ic]);
        ntstore4(cd, &out4[id]);
        return;
    }
    const int b = bid >> 8;          // 256 hist blocks per batch
    const int x = bid & 255;
    const int w = tid >> 6, ln = tid & 63;
    if (tid < 5) lh_win[tid] = 0;
    if (tid == 0) l_cnt = 0;
    __syncthreads();
    const size_t base4 = (size_t)b * n4 + (size_t)x * 1024;
    const uint32_t elem0 = ((uint32_t)x * 1024u + (uint32_t)tid) * 4u;

    // ---- stream phase: 4 loads -> 16 bins -> 4 NT stores, no atomics ----
    float4 v0 = cost4[base4 + 0 * 256 + tid];
    float4 v1 = cost4[base4 + 1 * 256 + tid];
    float4 v2 = cost4[base4 + 2 * 256 + tid];
    float4 v3 = cost4[base4 + 3 * 256 + tid];

    uint32_t b00 = costBin(v0.x), b01 = costBin(v0.y), b02 = costBin(v0.z), b03 = costBin(v0.w);
    uint32_t b10 = costBin(v1.x), b11 = costBin(v1.y), b12 = costBin(v1.z), b13 = costBin(v1.w);
    uint32_t b20 = costBin(v2.x), b21 = costBin(v2.y), b22 = costBin(v2.z), b23 = costBin(v2.w);
    uint32_t b30 = costBin(v3.x), b31 = costBin(v3.y), b32 = costBin(v3.z), b33 = costBin(v3.w);

    uint32_t below =
        (b00 < SPEC_LO) + (b01 < SPEC_LO) + (b02 < SPEC_LO) + (b03 < SPEC_LO) +
        (b10 < SPEC_LO) + (b11 < SPEC_LO) + (b12 < SPEC_LO) + (b13 < SPEC_LO) +
        (b20 < SPEC_LO) + (b21 < SPEC_LO) + (b22 < SPEC_LO) + (b23 < SPEC_LO) +
        (b30 < SPEC_LO) + (b31 < SPEC_LO) + (b32 < SPEC_LO) + (b33 < SPEC_LO);

    float4 o0, o1, o2, o3;
    o0.x = (b00 < SPEC_HI) ? v0.x : 0.0f; o0.y = (b01 < SPEC_HI) ? v0.y : 0.0f;
    o0.z = (b02 < SPEC_HI) ? v0.z : 0.0f; o0.w = (b03 < SPEC_HI) ? v0.w : 0.0f;
    o1.x = (b10 < SPEC_HI) ? v1.x : 0.0f; o1.y = (b11 < SPEC_HI) ? v1.y : 0.0f;
    o1.z = (b12 < SPEC_HI) ? v1.z : 0.0f; o1.w = (b13 < SPEC_HI) ? v1.w : 0.0f;
    o2.x = (b20 < SPEC_HI) ? v2.x : 0.0f; o2.y = (b21 < SPEC_HI) ? v2.y : 0.0f;
    o2.z = (b22 < SPEC_HI) ? v2.z : 0.0f; o2.w = (b23 < SPEC_HI) ? v2.w : 0.0f;
    o3.x = (b30 < SPEC_HI) ? v3.x : 0.0f; o3.y = (b31 < SPEC_HI) ? v3.y : 0.0f;
    o3.z = (b32 < SPEC_HI) ? v3.z : 0.0f; o3.w = (b33 < SPEC_HI) ? v3.w : 0.0f;
    ntstore4(o0, &outc4[base4 + 0 * 256 + tid]);
    ntstore4(o1, &outc4[base4 + 1 * 256 + tid]);
    ntstore4(o2, &outc4[base4 + 2 * 256 + tid]);
    ntstore4(o3, &outc4[base4 + 3 * 256 + tid]);

    // ---- rare path: window candidates via 16-bit hitmask ----
    #define INWIN(bb) ((uint32_t)((bb) >= SPEC_LO && (bb) <= SPEC_HI))
    uint32_t hm = 0;
    hm |= INWIN(b00) << 0;  hm |= INWIN(b01) << 1;  hm |= INWIN(b02) << 2;  hm |= INWIN(b03) << 3;
    hm |= INWIN(b10) << 4;  hm |= INWIN(b11) << 5;  hm |= INWIN(b12) << 6;  hm |= INWIN(b13) << 7;
    hm |= INWIN(b20) << 8;  hm |= INWIN(b21) << 9;  hm |= INWIN(b22) << 10; hm |= INWIN(b23) << 11;
    hm |= INWIN(b30) << 12; hm |= INWIN(b31) << 13; hm |= INWIN(b32) << 14; hm |= INWIN(b33) << 15;
    #undef INWIN
    if (hm) {
        const float vals[16] = {v0.x, v0.y, v0.z, v0.w, v1.x, v1.y, v1.z, v1.w,
                                v2.x, v2.y, v2.z, v2.w, v3.x, v3.y, v3.z, v3.w};
        const uint32_t binv[16] = {b00, b01, b02, b03, b10, b11, b12, b13,
                                   b20, b21, b22, b23, b30, b31, b32, b33};
        while (hm) {
            const int k = __ffs(hm) - 1;
            hm &= hm - 1;
            atomicAdd(&lh_win[binv[k] - SPEC_LO], 1u);
            const uint32_t p = atomicAdd(&l_cnt, 1u);
            if (p < (uint32_t)LCAP) {
                l_cv[p] = __float_as_uint(vals[k]);
                // element index: chunk (k>>2) stride 1024 elems, lane j = k&3
                l_ci[p] = elem0 + ((uint32_t)(k >> 2)) * 1024u + (uint32_t)(k & 3);
            }
        }
    }

    // wave-reduce below, combine across 4 waves, one global atomic
    #pragma unroll
    for (int o = 1; o < 64; o <<= 1) below += (uint32_t)__shfl_xor((int)below, o);
    if (ln == 0) l_below[w] = below;
    __syncthreads();
    if (tid == 0)
        atomicAdd(&meta[b * 16 + 8],
                  l_below[0] + l_below[1] + l_below[2] + l_below[3]);
    if (tid < 5 && lh_win[tid])
        atomicAdd(&meta[b * 16 + 9 + tid], lh_win[tid]);
    const uint32_t tot = l_cnt;
    if (tid == 0 && tot > (uint32_t)LCAP) meta[b * 16 + 15] = 1u;  // -> miss
    const uint32_t n = (tot > (uint32_t)LCAP) ? (uint32_t)LCAP : tot;
    if (tid == 0) l_base = atomicAdd(&meta[b * 16 + 4], n);
    __syncthreads();
    uint32_t* cv = candv + (size_t)b * CAP;
    uint32_t* ci = candi + (size_t)b * CAP;
    const uint32_t gb = l_base;
    for (uint32_t i = tid; i < n; i += 256) {
        const uint32_t g = gb + i;
        if (g < (uint32_t)CAP) { cv[g] = l_cv[i]; ci[g] = l_ci[i]; }
    }
}

// ---- pass 2: validate + exact threshold + tie index + output fixup ----
__global__ __launch_bounds__(NT) void solve_kernel(
    uint32_t* __restrict__ meta,
    uint32_t* __restrict__ candv, uint32_t* __restrict__ candi,
    const float4* __restrict__ cost4, float* __restrict__ outc,
    float4* __restrict__ outc4, int n4, uint32_t K, int N) {
    const int b = blockIdx.x;
    uint32_t* mb = meta + b * 16;
    const uint32_t* cv = candv + (size_t)b * CAP;
    const uint32_t* ci = candi + (size_t)b * CAP;
    __shared__ uint32_t scv[LDSCV];
    __shared__ uint32_t hh[TIECAP];         // slow hist / descent / ties
    __shared__ uint32_t pref[HBINS];
    __shared__ uint32_t sw[4 * NW];
    __shared__ uint32_t s_q, s_lo, s_need, s_range, s_tiecnt, s_res, s_cnt;
    const int t = threadIdx.x;
    const int w = t >> 6, ln = t & 63;

    // -- validate speculation from below/win counts --
    const uint32_t below = mb[8];
    const uint32_t over = mb[15];
    const uint32_t c0 = mb[4];
    uint32_t win[5];
    #pragma unroll
    for (int i = 0; i < 5; ++i) win[i] = mb[9 + i];
    int qrel = -1;   // window-relative crossing bin; -1 = below, 5 = above
    {
        uint32_t cum = below;
        if (K <= cum) qrel = -1;
        else {
            qrel = 5;
            #pragma unroll
            for (int i = 0; i < 5; ++i) {
                if (K > cum && K <= cum + win[i]) { qrel = i; break; }
                cum += win[i];
            }
        }
    }
    const bool hit = (qrel >= 1 && qrel <= 3) && !over && (c0 <= (uint32_t)CAP);

    uint32_t cnt, need0;
    if (hit) {
        need0 = K - below;
        cnt = c0;
    } else {
        // slow path (not taken for uniform data): full hist + re-gather
        for (int i = t; i < HBINS; i += NT) hh[i] = 0;
        __syncthreads();
        for (uint32_t i4 = (uint32_t)t; i4 < (uint32_t)n4; i4 += NT) {
            const float4 v = cost4[(size_t)b * n4 + i4];
            atomicAdd(&hh[costBin(v.x)], 1u);
            atomicAdd(&hh[costBin(v.y)], 1u);
            atomicAdd(&hh[costBin(v.z)], 1u);
            atomicAdd(&hh[costBin(v.w)], 1u);
        }
        __syncthreads();
        // prefix over 512 bins, one per thread
        const uint32_t hv = hh[t];
        uint32_t incl = hv;
        #pragma unroll
        for (int o = 1; o < 64; o <<= 1) {
            const uint32_t u = (uint32_t)__shfl_up((int)incl, o);
            if (ln >= o) incl += u;
        }
        if (ln == 63) sw[w] = incl;
        if (t == 0) s_q = HBINS - 1;
        __syncthreads();
        uint32_t wbase = 0;
        for (int i = 0; i < w; ++i) wbase += sw[i];
        incl += wbase;
        pref[t] = incl;
        __syncthreads();
        if (K > incl - hv && K <= incl) s_q = (uint32_t)t;
        __syncthreads();
        const uint32_t q = s_q;
        const uint32_t lob = (q > 0) ? q - 1 : 0;
        const uint32_t hib = (q < HBINS - 1) ? q + 1 : (HBINS - 1);
        need0 = K - ((lob > 0) ? pref[lob - 1] : 0u);
        if (t == 0) s_cnt = 0;
        __syncthreads();
        uint32_t* wcv = candv + (size_t)b * CAP;
        uint32_t* wci = candi + (size_t)b * CAP;
        for (uint32_t i4 = (uint32_t)t; i4 < (uint32_t)n4; i4 += NT) {
            const float4 v = cost4[(size_t)b * n4 + i4];
            const float xx[4] = {v.x, v.y, v.z, v.w};
            #pragma unroll
            for (int j = 0; j < 4; ++j) {
                const uint32_t bi = costBin(xx[j]);
                if (bi >= lob && bi <= hib) {
                    const uint32_t p = atomicAdd(&s_cnt, 1u);
                    if (p < (uint32_t)CAP) {
                        wcv[p] = __float_as_uint(xx[j]);
                        wci[p] = i4 * 4u + (uint32_t)j;
                    }
                }
            }
        }
        __syncthreads();
        cnt = (s_cnt > (uint32_t)CAP) ? (uint32_t)CAP : s_cnt;
    }

    // -- stage candidate values in LDS; block min/max of cost bits --
    uint32_t mn = 0xFFFFFFFFu, mx = 0u;
    for (uint32_t j = t; j < cnt; j += NT) {
        const uint32_t v = cv[j];
        if (j < (uint32_t)LDSCV) scv[j] = v;
        mn = (v < mn) ? v : mn;
        mx = (v > mx) ? v : mx;
    }
    #pragma unroll
    for (int o = 1; o < 64; o <<= 1) {
        const uint32_t a = (uint32_t)__shfl_xor((int)mn, o);
        const uint32_t z = (uint32_t)__shfl_xor((int)mx, o);
        mn = (a < mn) ? a : mn;
        mx = (z > mx) ? z : mx;
    }
    if (ln == 0) { sw[w] = mn; sw[NW + w] = mx; }
    __syncthreads();
    uint32_t lo = sw[0], hix = sw[NW];
    #pragma unroll
    for (int i = 1; i < NW; ++i) {
        lo = (sw[i] < lo) ? sw[i] : lo;
        hix = (sw[NW + i] > hix) ? sw[NW + i] : hix;
    }
    uint32_t range = hix - lo + 1u;
    uint32_t need = need0;

    // -- histogram descent: exact need-th smallest cost-bit value --
    while (range > 1u) {
        const int bits = 32 - __clz((int)(range - 1u));
        const int shift = (bits > 11) ? (bits - 11) : 0;
        for (int i = t; i < TIECAP; i += NT) hh[i] = 0;
        __syncthreads();
        for (uint32_t j = t; j < cnt; j += NT) {
            const uint32_t v = (j < (uint32_t)LDSCV) ? scv[j] : cv[j];
            const uint32_t d = v - lo;
            if (v >= lo && d < range) atomicAdd(&hh[d >> shift], 1u);
        }
        __syncthreads();
        uint32_t hv4[4];
        uint32_t csum = 0;
        #pragma unroll
        for (int i = 0; i < 4; ++i) { hv4[i] = hh[t * 4 + i]; csum += hv4[i]; }
        uint32_t inc2 = csum;
        #pragma unroll
        for (int o = 1; o < 64; o <<= 1) {
            const uint32_t up = (uint32_t)__shfl_up((int)inc2, o);
            if (ln >= o) inc2 += up;
        }
        if (ln == 63) sw[w] = inc2;
        // termination guard: defaults in case no crossing (corrupt input)
        if (t == 0) { s_lo = lo; s_need = 1u; s_range = 1u; }
        __syncthreads();
        uint32_t wpre = 0;
        for (int i = 0; i < w; ++i) wpre += sw[i];
        const uint32_t before = wpre + inc2 - csum;
        if (before < need && before + csum >= need) {
            uint32_t cum = before;
            #pragma unroll
            for (int i = 0; i < 4; ++i) {
                if (cum + hv4[i] >= need) {
                    const uint32_t qq = (uint32_t)(t * 4 + i);
                    const uint32_t off = qq << shift;
                    s_lo = lo + off;
                    s_need = need - cum;
                    const uint32_t span = range - off;
                    s_range = (span < (1u << shift)) ? span : (1u << shift);
                    break;
                }
                cum += hv4[i];
            }
        }
        __syncthreads();
        lo = s_lo; need = s_need; range = s_range;
        __syncthreads();
    }
    const uint32_t thr = impBits(__uint_as_float(lo));

    // -- count gt/eq; min/max tie index --
    uint32_t cg = 0, ce = 0, imn = 0xFFFFFFFFu, imx = 0u;
    for (uint32_t j = t; j < cnt; j += NT) {
        const uint32_t v = (j < (uint32_t)LDSCV) ? scv[j] : cv[j];
        const uint32_t ib = impBits(__uint_as_float(v));
        if (ib > thr) cg++;
        else if (ib == thr) {
            ce++;
            const uint32_t ix = ci[j];
            imn = (ix < imn) ? ix : imn;
            imx = (ix > imx) ? ix : imx;
        }
    }
    #pragma unroll
    for (int o = 1; o < 64; o <<= 1) {
        cg += (uint32_t)__shfl_xor((int)cg, o);
        ce += (uint32_t)__shfl_xor((int)ce, o);
        const uint32_t a = (uint32_t)__shfl_xor((int)imn, o);
        const uint32_t z = (uint32_t)__shfl_xor((int)imx, o);
        imn = (a < imn) ? a : imn;
        imx = (z > imx) ? z : imx;
    }
    if (ln == 0) { sw[w] = cg; sw[NW + w] = ce; sw[2 * NW + w] = imn; sw[3 * NW + w] = imx; }
    __syncthreads();
    uint32_t gt = 0, eq = 0, imin = 0xFFFFFFFFu, imax = 0u;
    #pragma unroll
    for (int i = 0; i < NW; ++i) {
        gt += sw[i];
        eq += sw[NW + i];
        imin = (sw[2 * NW + i] < imin) ? sw[2 * NW + i] : imin;
        imax = (sw[3 * NW + i] > imax) ? sw[3 * NW + i] : imax;
    }
    __syncthreads();

    const uint32_t m = need0 - gt;  // # threshold-equal elements to take
    uint32_t idxthr = 0xFFFFFFFFu;
    if (m < eq) {
        if (m == 1) {
            idxthr = imin;
        } else {
            // gather tie indices into LDS, O(eq) rank-select
            if (t == 0) { s_tiecnt = 0; s_res = imin; }
            __syncthreads();
            for (uint32_t j = t; j < cnt; j += NT) {
                const uint32_t v = (j < (uint32_t)LDSCV) ? scv[j] : cv[j];
                if (impBits(__uint_as_float(v)) == thr) {
                    const uint32_t p = atomicAdd(&s_tiecnt, 1u);
                    if (p < (uint32_t)TIECAP) hh[p] = ci[j];
                }
            }
            __syncthreads();
            const uint32_t tc = s_tiecnt;
            if (tc <= (uint32_t)TIECAP) {
                for (uint32_t p = t; p < tc; p += NT) {
                    const uint32_t x = hh[p];
                    uint32_t r = 0;
                    for (uint32_t q2 = 0; q2 < tc; ++q2) r += (hh[q2] < x) ? 1u : 0u;
                    if (r == m - 1) s_res = x;  // unique (flat indices distinct)
                }
                __syncthreads();
                idxthr = s_res;
            } else {
                // unreachable in practice: bsearch m-th smallest index
                uint32_t l2 = imin, h2 = imax;
                while (l2 < h2) {
                    const uint32_t mid = l2 + ((h2 - l2) >> 1);
                    uint32_t c = 0;
                    for (uint32_t j = t; j < cnt; j += NT) {
                        const uint32_t v = (j < (uint32_t)LDSCV) ? scv[j] : cv[j];
                        c += (impBits(__uint_as_float(v)) == thr && ci[j] <= mid) ? 1u : 0u;
                    }
                    #pragma unroll
                    for (int o = 1; o < 64; o <<= 1) c += (uint32_t)__shfl_xor((int)c, o);
                    if (ln == 0) sw[w] = c;
                    __syncthreads();
                    uint32_t tot = 0;
                    for (int i = 0; i < NW; ++i) tot += sw[i];
                    __syncthreads();
                    if (tot >= m) h2 = mid; else l2 = mid + 1;
                }
                idxthr = l2;
            }
        }
    }

    // -- output fixup (thr, idxthr are block-uniform) --
    if (hit) {
        // scatter definitive values for the candidates only
        float* ob = outc + (size_t)b * N;
        for (uint32_t j = t; j < cnt; j += NT) {
            const uint32_t vbits = (j < (uint32_t)LDSCV) ? scv[j] : cv[j];
            const uint32_t ix = ci[j];
            const uint32_t ib = impBits(__uint_as_float(vbits));
            const bool keep = (ib > thr) || (ib == thr && ix <= idxthr);
            ob[ix] = keep ? __uint_as_float(vbits) : 0.0f;
        }
    } else {
        // full re-mask of this batch (slow, correctness-only)
        const float4* cc4 = cost4 + (size_t)b * n4;
        float4* oc4 = outc4 + (size_t)b * n4;
        for (uint32_t i4 = (uint32_t)t; i4 < (uint32_t)n4; i4 += NT) {
            float4 v = cc4[i4];
            const uint32_t e0 = i4 * 4u;
            float4 o;
            uint32_t bx;
            bx = impBits(v.x); o.x = (bx > thr || (bx == thr && e0 + 0 <= idxthr)) ? v.x : 0.0f;
            bx = impBits(v.y); o.y = (bx > thr || (bx == thr && e0 + 1 <= idxthr)) ? v.y : 0.0f;
            bx = impBits(v.z); o.z = (bx > thr || (bx == thr && e0 + 2 <= idxthr)) ? v.z : 0.0f;
            bx = impBits(v.w); o.w = (bx > thr || (bx == thr && e0 + 3 <= idxthr)) ? v.w : 0.0f;
            oc4[i4] = o;
        }
    }
}

extern "C" void kernel_launch(void* const* d_in, const int* in_sizes, int n_in,
                              void* d_out, int out_size, void* d_ws, size_t ws_size,
                              hipStream_t stream) {
    const float* src  = (const float*)d_in[0];
    const float* tgt  = (const float*)d_in[1];
    const float* cost = (const float*)d_in[2];
    const int srcN = in_sizes[0];
    const int tgtN = in_sizes[1];
    const int costN = in_sizes[2];
    const int S = 1024, T = 1024;
    const int N = S * T;
    const int B = costN / N;
    const uint32_t K = (uint32_t)(((uint64_t)N * 2ull) / 10ull);  // int(N*0.2)

    float* out = (float*)d_out;

    uint32_t* meta  = (uint32_t*)d_ws;
    uint32_t* candv = meta + (size_t)B * 16;
    uint32_t* candi = candv + (size_t)B * CAP;

    const int n4 = N / 4;               // 262144 = 2^18
    const int s4 = srcN / 4, t4 = tgtN / 4;
    const int nHist = B * (n4 / 1024);  // 256 blocks per batch
    const int nCopy = (s4 + t4) / 1024; // exact multiple (1024 blocks)

    float* outc = out + (size_t)srcN + tgtN;

    dim3 blk(256, 1, 1);

    init_kernel<<<(B * 16 + 255) / 256, blk, 0, stream>>>(meta, B);
    histgather_kernel<<<nHist + nCopy, blk, 0, stream>>>(
        (const float4*)cost, (const float4*)src, (const float4*)tgt,
        (float4*)out, (float4*)outc, meta, candv, candi, n4, nHist, s4);
    solve_kernel<<<B, NT, 0, stream>>>(meta, candv, candi,
                                       (const float4*)cost, outc,
                                       (float4*)outc, n4, K, N);
}

// Round 14
// 73.845 us; speedup vs baseline: 1.0764x; 1.0764x over previous
//
#include <hip/hip_runtime.h>
#include <stdint.h>

// ImportanceSparsification: per-batch top-k (k = 0.2*S*T) of 1/(cost+1e-8),
// out = (source, target, cost*mask). Exact selection with jax top_k
// tie-break (lowest flat index among equal importance values).
//
// R13 -> R14: five rounds of micro-fixes (atomics, MLP, NT, phase-split)
// all bounced off a ~50us floor for the FUSED stream+count+gather block,
// with nothing saturated (HBM 2.5/6.9 TB/s, VALU 15%, occ 63%). Theory:
// the fusion itself is the cost (dependent chain + LDS/reduce tail on
// every streaming block). R14 role-splits one dispatch into:
//   G (1024 blocks): count below/win + gather candidates, no output store
//   P (4096 blocks): provisional mask, pure stream (no LDS/atomic/barrier)
//   C (1024 blocks): src/tgt copy, pure stream
// solve(+candidate fixup tail) unchanged from R13; fixup is ordered after
// P by the dispatch boundary (no race). Cost is read twice (G+P) but the
// second read is L3-resident.

static constexpr int CAP   = 32768;   // per-batch candidate cap (global)
static constexpr int LCAP  = 1024;    // per-G-block candidate staging (LDS)
static constexpr int LDSCV = 12288;   // solve: LDS-staged candidate values
static constexpr int TIECAP = 2048;   // solve: LDS tie / slow-path hist
static constexpr int HBINS = 512;     // slow-path linear cost bins
static constexpr int NT    = 512;     // solve block size
static constexpr int NW    = NT / 64; // waves in solve block
static constexpr uint32_t SPEC_LO = 100;  // speculative window (bins of 512)
static constexpr uint32_t SPEC_HI = 104;
static constexpr float EPSF = 1e-8f;

typedef float f32x4 __attribute__((ext_vector_type(4)));

__device__ __forceinline__ float4 ntload4(const float4* p) {
    f32x4 r = __builtin_nontemporal_load(reinterpret_cast<const f32x4*>(p));
    float4 v; v.x = r.x; v.y = r.y; v.z = r.z; v.w = r.w;
    return v;
}
__device__ __forceinline__ void ntstore4(const float4& v, float4* p) {
    f32x4 t; t.x = v.x; t.y = v.y; t.z = v.z; t.w = v.w;
    __builtin_nontemporal_store(t, reinterpret_cast<f32x4*>(p));
}

__device__ __forceinline__ uint32_t impBits(float c) {
    // IEEE-correct f32 ops (no fast-math) -> bit-exact vs numpy reference
    return __float_as_uint(1.0f / (c + EPSF));
}

__device__ __forceinline__ uint32_t costBin(float x) {
    uint32_t bi = (uint32_t)(x * (float)HBINS);  // x in [0,1)
    return bi > (HBINS - 1) ? (HBINS - 1) : bi;
}

// meta per batch (16 u32):
// [4]=candcnt [8]=below [9..13]=win[5] [15]=stage_overflow

// ---- pass 0: zero meta ----
__global__ __launch_bounds__(256) void init_kernel(
    uint32_t* __restrict__ meta, int B) {
    const int i = blockIdx.x * 256 + threadIdx.x;
    if (i < B * 16) meta[i] = 0u;
}

// ---- pass 1: role-split stream dispatch ----
// blocks [0, nG):            G role — count + gather (64 blocks/batch)
// blocks [nG, nG+nP):        P role — provisional masked output (pure stream)
// blocks [nG+nP, nG+nP+nC):  C role — src/tgt copy (pure stream)
__global__ __launch_bounds__(256) void stream_kernel(
    const float4* __restrict__ cost4, const float4* __restrict__ src4,
    const float4* __restrict__ tgt4, float4* __restrict__ out4,
    float4* __restrict__ outc4, uint32_t* __restrict__ meta,
    uint32_t* __restrict__ candv, uint32_t* __restrict__ candi,
    int n4, int nG, int nP, int s4) {
    const int bid = blockIdx.x;
    const int tid = threadIdx.x;

    if (bid >= nG) {
        if (bid < nG + nP) {
            // ---- P role: provisional mask, 1024 f4/block, pure stream ----
            const size_t i0 = (size_t)(bid - nG) * 1024;
            float4 v0 = cost4[i0 + 0 * 256 + tid];
            float4 v1 = cost4[i0 + 1 * 256 + tid];
            float4 v2 = cost4[i0 + 2 * 256 + tid];
            float4 v3 = cost4[i0 + 3 * 256 + tid];
            float4 o0, o1, o2, o3;
            o0.x = (costBin(v0.x) < SPEC_HI) ? v0.x : 0.0f;
            o0.y = (costBin(v0.y) < SPEC_HI) ? v0.y : 0.0f;
            o0.z = (costBin(v0.z) < SPEC_HI) ? v0.z : 0.0f;
            o0.w = (costBin(v0.w) < SPEC_HI) ? v0.w : 0.0f;
            o1.x = (costBin(v1.x) < SPEC_HI) ? v1.x : 0.0f;
            o1.y = (costBin(v1.y) < SPEC_HI) ? v1.y : 0.0f;
            o1.z = (costBin(v1.z) < SPEC_HI) ? v1.z : 0.0f;
            o1.w = (costBin(v1.w) < SPEC_HI) ? v1.w : 0.0f;
            o2.x = (costBin(v2.x) < SPEC_HI) ? v2.x : 0.0f;
            o2.y = (costBin(v2.y) < SPEC_HI) ? v2.y : 0.0f;
            o2.z = (costBin(v2.z) < SPEC_HI) ? v2.z : 0.0f;
            o2.w = (costBin(v2.w) < SPEC_HI) ? v2.w : 0.0f;
            o3.x = (costBin(v3.x) < SPEC_HI) ? v3.x : 0.0f;
            o3.y = (costBin(v3.y) < SPEC_HI) ? v3.y : 0.0f;
            o3.z = (costBin(v3.z) < SPEC_HI) ? v3.z : 0.0f;
            o3.w = (costBin(v3.w) < SPEC_HI) ? v3.w : 0.0f;
            ntstore4(o0, &outc4[i0 + 0 * 256 + tid]);
            ntstore4(o1, &outc4[i0 + 1 * 256 + tid]);
            ntstore4(o2, &outc4[i0 + 2 * 256 + tid]);
            ntstore4(o3, &outc4[i0 + 3 * 256 + tid]);
        } else {
            // ---- C role: src/tgt copy, 1024 f4/block, pure stream ----
            const int i0 = (bid - nG - nP) * 1024;
            const int ia = i0 + 0 * 256 + tid;
            const int ib = i0 + 1 * 256 + tid;
            const int ic = i0 + 2 * 256 + tid;
            const int id = i0 + 3 * 256 + tid;
            float4 ca = (ia < s4) ? ntload4(&src4[ia]) : ntload4(&tgt4[ia - s4]);
            float4 cb = (ib < s4) ? ntload4(&src4[ib]) : ntload4(&tgt4[ib - s4]);
            float4 cc = (ic < s4) ? ntload4(&src4[ic]) : ntload4(&tgt4[ic - s4]);
            float4 cd = (id < s4) ? ntload4(&src4[id]) : ntload4(&tgt4[id - s4]);
            ntstore4(ca, &out4[ia]);
            ntstore4(cb, &out4[ib]);
            ntstore4(cc, &out4[ic]);
            ntstore4(cd, &out4[id]);
        }
        return;
    }

    // ---- G role: count below/win + gather candidates; no output store ----
    __shared__ uint32_t l_cv[LCAP];
    __shared__ uint32_t l_ci[LCAP];
    __shared__ uint32_t lh_win[5];
    __shared__ uint32_t l_below[4];
    __shared__ uint32_t l_cnt, l_base;
    const int b = bid >> 6;          // 64 G blocks per batch
    const int x = bid & 63;
    const int w = tid >> 6, ln = tid & 63;
    if (tid < 5) lh_win[tid] = 0;
    if (tid == 0) l_cnt = 0;
    __syncthreads();
    const size_t base4 = (size_t)b * n4 + (size_t)x * 4096;
    uint32_t below = 0;
    #pragma unroll
    for (int r = 0; r < 4; ++r) {
        const size_t r0 = base4 + (size_t)r * 1024;
        float4 v0 = cost4[r0 + 0 * 256 + tid];
        float4 v1 = cost4[r0 + 1 * 256 + tid];
        float4 v2 = cost4[r0 + 2 * 256 + tid];
        float4 v3 = cost4[r0 + 3 * 256 + tid];
        uint32_t bb[16];
        bb[0]  = costBin(v0.x); bb[1]  = costBin(v0.y); bb[2]  = costBin(v0.z); bb[3]  = costBin(v0.w);
        bb[4]  = costBin(v1.x); bb[5]  = costBin(v1.y); bb[6]  = costBin(v1.z); bb[7]  = costBin(v1.w);
        bb[8]  = costBin(v2.x); bb[9]  = costBin(v2.y); bb[10] = costBin(v2.z); bb[11] = costBin(v2.w);
        bb[12] = costBin(v3.x); bb[13] = costBin(v3.y); bb[14] = costBin(v3.z); bb[15] = costBin(v3.w);
        uint32_t hm = 0;
        #pragma unroll
        for (int k = 0; k < 16; ++k) {
            below += (bb[k] < SPEC_LO) ? 1u : 0u;
            hm |= ((uint32_t)(bb[k] >= SPEC_LO && bb[k] <= SPEC_HI)) << k;
        }
        if (hm) {
            const float vals[16] = {v0.x, v0.y, v0.z, v0.w, v1.x, v1.y, v1.z, v1.w,
                                    v2.x, v2.y, v2.z, v2.w, v3.x, v3.y, v3.z, v3.w};
            // elem index within batch for slot k (chunk q=k>>2, lane j=k&3):
            // ((x*4096 + r*1024 + q*256 + tid) * 4 + j)
            while (hm) {
                const int k = __ffs(hm) - 1;
                hm &= hm - 1;
                atomicAdd(&lh_win[bb[k] - SPEC_LO], 1u);
                const uint32_t p = atomicAdd(&l_cnt, 1u);
                if (p < (uint32_t)LCAP) {
                    l_cv[p] = __float_as_uint(vals[k]);
                    l_ci[p] = ((uint32_t)x * 4096u + (uint32_t)r * 1024u +
                               ((uint32_t)(k >> 2)) * 256u + (uint32_t)tid) * 4u +
                              (uint32_t)(k & 3);
                }
            }
        }
    }
    // wave-reduce below, combine across 4 waves, one global atomic
    #pragma unroll
    for (int o = 1; o < 64; o <<= 1) below += (uint32_t)__shfl_xor((int)below, o);
    if (ln == 0) l_below[w] = below;
    __syncthreads();
    if (tid == 0)
        atomicAdd(&meta[b * 16 + 8],
                  l_below[0] + l_below[1] + l_below[2] + l_below[3]);
    if (tid < 5 && lh_win[tid])
        atomicAdd(&meta[b * 16 + 9 + tid], lh_win[tid]);
    const uint32_t tot = l_cnt;
    if (tid == 0 && tot > (uint32_t)LCAP) meta[b * 16 + 15] = 1u;  // -> miss
    const uint32_t n = (tot > (uint32_t)LCAP) ? (uint32_t)LCAP : tot;
    if (tid == 0) l_base = atomicAdd(&meta[b * 16 + 4], n);
    __syncthreads();
    uint32_t* cv = candv + (size_t)b * CAP;
    uint32_t* ci = candi + (size_t)b * CAP;
    const uint32_t gb = l_base;
    for (uint32_t i = tid; i < n; i += 256) {
        const uint32_t g = gb + i;
        if (g < (uint32_t)CAP) { cv[g] = l_cv[i]; ci[g] = l_ci[i]; }
    }
}

// ---- pass 2: validate + exact threshold + tie index + output fixup ----
__global__ __launch_bounds__(NT) void solve_kernel(
    uint32_t* __restrict__ meta,
    uint32_t* __restrict__ candv, uint32_t* __restrict__ candi,
    const float4* __restrict__ cost4, float* __restrict__ outc,
    float4* __restrict__ outc4, int n4, uint32_t K, int N) {
    const int b = blockIdx.x;
    uint32_t* mb = meta + b * 16;
    const uint32_t* cv = candv + (size_t)b * CAP;
    const uint32_t* ci = candi + (size_t)b * CAP;
    __shared__ uint32_t scv[LDSCV];
    __shared__ uint32_t hh[TIECAP];         // slow hist / descent / ties
    __shared__ uint32_t pref[HBINS];
    __shared__ uint32_t sw[4 * NW];
    __shared__ uint32_t s_q, s_lo, s_need, s_range, s_tiecnt, s_res, s_cnt;
    const int t = threadIdx.x;
    const int w = t >> 6, ln = t & 63;

    // -- validate speculation from below/win counts --
    const uint32_t below = mb[8];
    const uint32_t over = mb[15];
    const uint32_t c0 = mb[4];
    uint32_t win[5];
    #pragma unroll
    for (int i = 0; i < 5; ++i) win[i] = mb[9 + i];
    int qrel = -1;   // window-relative crossing bin; -1 = below, 5 = above
    {
        uint32_t cum = below;
        if (K <= cum) qrel = -1;
        else {
            qrel = 5;
            #pragma unroll
            for (int i = 0; i < 5; ++i) {
                if (K > cum && K <= cum + win[i]) { qrel = i; break; }
                cum += win[i];
            }
        }
    }
    const bool hit = (qrel >= 1 && qrel <= 3) && !over && (c0 <= (uint32_t)CAP);

    uint32_t cnt, need0;
    if (hit) {
        need0 = K - below;
        cnt = c0;
    } else {
        // slow path (not taken for uniform data): full hist + re-gather
        for (int i = t; i < HBINS; i += NT) hh[i] = 0;
        __syncthreads();
        for (uint32_t i4 = (uint32_t)t; i4 < (uint32_t)n4; i4 += NT) {
            const float4 v = cost4[(size_t)b * n4 + i4];
            atomicAdd(&hh[costBin(v.x)], 1u);
            atomicAdd(&hh[costBin(v.y)], 1u);
            atomicAdd(&hh[costBin(v.z)], 1u);
            atomicAdd(&hh[costBin(v.w)], 1u);
        }
        __syncthreads();
        // prefix over 512 bins, one per thread
        const uint32_t hv = hh[t];
        uint32_t incl = hv;
        #pragma unroll
        for (int o = 1; o < 64; o <<= 1) {
            const uint32_t u = (uint32_t)__shfl_up((int)incl, o);
            if (ln >= o) incl += u;
        }
        if (ln == 63) sw[w] = incl;
        if (t == 0) s_q = HBINS - 1;
        __syncthreads();
        uint32_t wbase = 0;
        for (int i = 0; i < w; ++i) wbase += sw[i];
        incl += wbase;
        pref[t] = incl;
        __syncthreads();
        if (K > incl - hv && K <= incl) s_q = (uint32_t)t;
        __syncthreads();
        const uint32_t q = s_q;
        const uint32_t lob = (q > 0) ? q - 1 : 0;
        const uint32_t hib = (q < HBINS - 1) ? q + 1 : (HBINS - 1);
        need0 = K - ((lob > 0) ? pref[lob - 1] : 0u);
        if (t == 0) s_cnt = 0;
        __syncthreads();
        uint32_t* wcv = candv + (size_t)b * CAP;
        uint32_t* wci = candi + (size_t)b * CAP;
        for (uint32_t i4 = (uint32_t)t; i4 < (uint32_t)n4; i4 += NT) {
            const float4 v = cost4[(size_t)b * n4 + i4];
            const float xx[4] = {v.x, v.y, v.z, v.w};
            #pragma unroll
            for (int j = 0; j < 4; ++j) {
                const uint32_t bi = costBin(xx[j]);
                if (bi >= lob && bi <= hib) {
                    const uint32_t p = atomicAdd(&s_cnt, 1u);
                    if (p < (uint32_t)CAP) {
                        wcv[p] = __float_as_uint(xx[j]);
                        wci[p] = i4 * 4u + (uint32_t)j;
                    }
                }
            }
        }
        __syncthreads();
        cnt = (s_cnt > (uint32_t)CAP) ? (uint32_t)CAP : s_cnt;
    }

    // -- stage candidate values in LDS; block min/max of cost bits --
    uint32_t mn = 0xFFFFFFFFu, mx = 0u;
    for (uint32_t j = t; j < cnt; j += NT) {
        const uint32_t v = cv[j];
        if (j < (uint32_t)LDSCV) scv[j] = v;
        mn = (v < mn) ? v : mn;
        mx = (v > mx) ? v : mx;
    }
    #pragma unroll
    for (int o = 1; o < 64; o <<= 1) {
        const uint32_t a = (uint32_t)__shfl_xor((int)mn, o);
        const uint32_t z = (uint32_t)__shfl_xor((int)mx, o);
        mn = (a < mn) ? a : mn;
        mx = (z > mx) ? z : mx;
    }
    if (ln == 0) { sw[w] = mn; sw[NW + w] = mx; }
    __syncthreads();
    uint32_t lo = sw[0], hix = sw[NW];
    #pragma unroll
    for (int i = 1; i < NW; ++i) {
        lo = (sw[i] < lo) ? sw[i] : lo;
        hix = (sw[NW + i] > hix) ? sw[NW + i] : hix;
    }
    uint32_t range = hix - lo + 1u;
    uint32_t need = need0;

    // -- histogram descent: exact need-th smallest cost-bit value --
    while (range > 1u) {
        const int bits = 32 - __clz((int)(range - 1u));
        const int shift = (bits > 11) ? (bits - 11) : 0;
        for (int i = t; i < TIECAP; i += NT) hh[i] = 0;
        __syncthreads();
        for (uint32_t j = t; j < cnt; j += NT) {
            const uint32_t v = (j < (uint32_t)LDSCV) ? scv[j] : cv[j];
            const uint32_t d = v - lo;
            if (v >= lo && d < range) atomicAdd(&hh[d >> shift], 1u);
        }
        __syncthreads();
        uint32_t hv4[4];
        uint32_t csum = 0;
        #pragma unroll
        for (int i = 0; i < 4; ++i) { hv4[i] = hh[t * 4 + i]; csum += hv4[i]; }
        uint32_t inc2 = csum;
        #pragma unroll
        for (int o = 1; o < 64; o <<= 1) {
            const uint32_t up = (uint32_t)__shfl_up((int)inc2, o);
            if (ln >= o) inc2 += up;
        }
        if (ln == 63) sw[w] = inc2;
        // termination guard: defaults in case no crossing (corrupt input)
        if (t == 0) { s_lo = lo; s_need = 1u; s_range = 1u; }
        __syncthreads();
        uint32_t wpre = 0;
        for (int i = 0; i < w; ++i) wpre += sw[i];
        const uint32_t before = wpre + inc2 - csum;
        if (before < need && before + csum >= need) {
            uint32_t cum = before;
            #pragma unroll
            for (int i = 0; i < 4; ++i) {
                if (cum + hv4[i] >= need) {
                    const uint32_t qq = (uint32_t)(t * 4 + i);
                    const uint32_t off = qq << shift;
                    s_lo = lo + off;
                    s_need = need - cum;
                    const uint32_t span = range - off;
                    s_range = (span < (1u << shift)) ? span : (1u << shift);
                    break;
                }
                cum += hv4[i];
            }
        }
        __syncthreads();
        lo = s_lo; need = s_need; range = s_range;
        __syncthreads();
    }
    const uint32_t thr = impBits(__uint_as_float(lo));

    // -- count gt/eq; min/max tie index --
    uint32_t cg = 0, ce = 0, imn = 0xFFFFFFFFu, imx = 0u;
    for (uint32_t j = t; j < cnt; j += NT) {
        const uint32_t v = (j < (uint32_t)LDSCV) ? scv[j] : cv[j];
        const uint32_t ib = impBits(__uint_as_float(v));
        if (ib > thr) cg++;
        else if (ib == thr) {
            ce++;
            const uint32_t ix = ci[j];
            imn = (ix < imn) ? ix : imn;
            imx = (ix > imx) ? ix : imx;
        }
    }
    #pragma unroll
    for (int o = 1; o < 64; o <<= 1) {
        cg += (uint32_t)__shfl_xor((int)cg, o);
        ce += (uint32_t)__shfl_xor((int)ce, o);
        const uint32_t a = (uint32_t)__shfl_xor((int)imn, o);
        const uint32_t z = (uint32_t)__shfl_xor((int)imx, o);
        imn = (a < imn) ? a : imn;
        imx = (z > imx) ? z : imx;
    }
    if (ln == 0) { sw[w] = cg; sw[NW + w] = ce; sw[2 * NW + w] = imn; sw[3 * NW + w] = imx; }
    __syncthreads();
    uint32_t gt = 0, eq = 0, imin = 0xFFFFFFFFu, imax = 0u;
    #pragma unroll
    for (int i = 0; i < NW; ++i) {
        gt += sw[i];
        eq += sw[NW + i];
        imin = (sw[2 * NW + i] < imin) ? sw[2 * NW + i] : imin;
        imax = (sw[3 * NW + i] > imax) ? sw[3 * NW + i] : imax;
    }
    __syncthreads();

    const uint32_t m = need0 - gt;  // # threshold-equal elements to take
    uint32_t idxthr = 0xFFFFFFFFu;
    if (m < eq) {
        if (m == 1) {
            idxthr = imin;
        } else {
            // gather tie indices into LDS, O(eq) rank-select
            if (t == 0) { s_tiecnt = 0; s_res = imin; }
            __syncthreads();
            for (uint32_t j = t; j < cnt; j += NT) {
                const uint32_t v = (j < (uint32_t)LDSCV) ? scv[j] : cv[j];
                if (impBits(__uint_as_float(v)) == thr) {
                    const uint32_t p = atomicAdd(&s_tiecnt, 1u);
                    if (p < (uint32_t)TIECAP) hh[p] = ci[j];
                }
            }
            __syncthreads();
            const uint32_t tc = s_tiecnt;
            if (tc <= (uint32_t)TIECAP) {
                for (uint32_t p = t; p < tc; p += NT) {
                    const uint32_t x = hh[p];
                    uint32_t r = 0;
                    for (uint32_t q2 = 0; q2 < tc; ++q2) r += (hh[q2] < x) ? 1u : 0u;
                    if (r == m - 1) s_res = x;  // unique (flat indices distinct)
                }
                __syncthreads();
                idxthr = s_res;
            } else {
                // unreachable in practice: bsearch m-th smallest index
                uint32_t l2 = imin, h2 = imax;
                while (l2 < h2) {
                    const uint32_t mid = l2 + ((h2 - l2) >> 1);
                    uint32_t c = 0;
                    for (uint32_t j = t; j < cnt; j += NT) {
                        const uint32_t v = (j < (uint32_t)LDSCV) ? scv[j] : cv[j];
                        c += (impBits(__uint_as_float(v)) == thr && ci[j] <= mid) ? 1u : 0u;
                    }
                    #pragma unroll
                    for (int o = 1; o < 64; o <<= 1) c += (uint32_t)__shfl_xor((int)c, o);
                    if (ln == 0) sw[w] = c;
                    __syncthreads();
                    uint32_t tot = 0;
                    for (int i = 0; i < NW; ++i) tot += sw[i];
                    __syncthreads();
                    if (tot >= m) h2 = mid; else l2 = mid + 1;
                }
                idxthr = l2;
            }
        }
    }

    // -- output fixup (thr, idxthr are block-uniform) --
    if (hit) {
        // scatter definitive values for the candidates only
        float* ob = outc + (size_t)b * N;
        for (uint32_t j = t; j < cnt; j += NT) {
            const uint32_t vbits = (j < (uint32_t)LDSCV) ? scv[j] : cv[j];
            const uint32_t ix = ci[j];
            const uint32_t ib = impBits(__uint_as_float(vbits));
            const bool keep = (ib > thr) || (ib == thr && ix <= idxthr);
            ob[ix] = keep ? __uint_as_float(vbits) : 0.0f;
        }
    } else {
        // full re-mask of this batch (slow, correctness-only)
        const float4* cc4 = cost4 + (size_t)b * n4;
        float4* oc4 = outc4 + (size_t)b * n4;
        for (uint32_t i4 = (uint32_t)t; i4 < (uint32_t)n4; i4 += NT) {
            float4 v = cc4[i4];
            const uint32_t e0 = i4 * 4u;
            float4 o;
            uint32_t bx;
            bx = impBits(v.x); o.x = (bx > thr || (bx == thr && e0 + 0 <= idxthr)) ? v.x : 0.0f;
            bx = impBits(v.y); o.y = (bx > thr || (bx == thr && e0 + 1 <= idxthr)) ? v.y : 0.0f;
            bx = impBits(v.z); o.z = (bx > thr || (bx == thr && e0 + 2 <= idxthr)) ? v.z : 0.0f;
            bx = impBits(v.w); o.w = (bx > thr || (bx == thr && e0 + 3 <= idxthr)) ? v.w : 0.0f;
            oc4[i4] = o;
        }
    }
}

extern "C" void kernel_launch(void* const* d_in, const int* in_sizes, int n_in,
                              void* d_out, int out_size, void* d_ws, size_t ws_size,
                              hipStream_t stream) {
    const float* src  = (const float*)d_in[0];
    const float* tgt  = (const float*)d_in[1];
    const float* cost = (const float*)d_in[2];
    const int srcN = in_sizes[0];
    const int tgtN = in_sizes[1];
    const int costN = in_sizes[2];
    const int S = 1024, T = 1024;
    const int N = S * T;
    const int B = costN / N;
    const uint32_t K = (uint32_t)(((uint64_t)N * 2ull) / 10ull);  // int(N*0.2)

    float* out = (float*)d_out;

    uint32_t* meta  = (uint32_t*)d_ws;
    uint32_t* candv = meta + (size_t)B * 16;
    uint32_t* candi = candv + (size_t)B * CAP;

    const int n4 = N / 4;               // 262144 = 2^18
    const int s4 = srcN / 4, t4 = tgtN / 4;
    const int nG = B * 64;              // 64 gather blocks per batch
    const int nP = (B * n4) / 1024;     // provisional-mask blocks
    const int nC = (s4 + t4) / 1024;    // copy blocks (exact multiple)

    float* outc = out + (size_t)srcN + tgtN;

    dim3 blk(256, 1, 1);

    init_kernel<<<(B * 16 + 255) / 256, blk, 0, stream>>>(meta, B);
    stream_kernel<<<nG + nP + nC, blk, 0, stream>>>(
        (const float4*)cost, (const float4*)src, (const float4*)tgt,
        (float4*)out, (float4*)outc, meta, candv, candi, n4, nG, nP, s4);
    solve_kernel<<<B, NT, 0, stream>>>(meta, candv, candi,
                                       (const float4*)cost, outc,
                                       (float4*)outc, n4, K, N);
}

// Round 15
// 72.762 us; speedup vs baseline: 1.0924x; 1.0149x over previous
//
#include <hip/hip_runtime.h>
#include <stdint.h>

// ImportanceSparsification: per-batch top-k (k = 0.2*S*T) of 1/(cost+1e-8),
// out = (source, target, cost*mask). Exact selection with jax top_k
// tie-break (lowest flat index among equal importance values).
//
// R14 -> R15:
//  - P/C stream roles reverted to the R6-proven shape: 1 float4/thread,
//    thin grid, REGULAR loads/stores (NT stores measured slower on gfx950;
//    fat 4-f4 blocks underfilled the machine: 3.2 TB/s vs R6's 5 TB/s).
//  - solve: stage only bins [q-1,q+1] (~6K cands; importance plateau is
//    provably inside) into LDS values+indices via ballot-aggregated
//    appends; descent/count/tie/fixup passes all LDS-only. Provisional
//    keep rule becomes bin <= SPEC_LO+1 (consistent with filtered fixup
//    for q in {101,102,103}; spec-miss still full-re-masks).

static constexpr int CAP   = 32768;   // per-batch candidate cap (global)
static constexpr int LCAP  = 1024;    // per-G-block candidate staging (LDS)
static constexpr int SCAP  = 6656;    // solve: LDS staged candidate cap
static constexpr int TIECAP = 2048;   // solve: LDS tie list cap
static constexpr int HBINS = 512;     // linear cost bins
static constexpr int NT    = 512;     // solve block size
static constexpr int NW    = NT / 64; // waves in solve block
static constexpr uint32_t SPEC_LO = 100;  // speculative window (bins of 512)
static constexpr uint32_t SPEC_HI = 104;
static constexpr float EPSF = 1e-8f;

__device__ __forceinline__ uint32_t impBits(float c) {
    // IEEE-correct f32 ops (no fast-math) -> bit-exact vs numpy reference
    return __float_as_uint(1.0f / (c + EPSF));
}

__device__ __forceinline__ uint32_t costBin(float x) {
    uint32_t bi = (uint32_t)(x * (float)HBINS);  // x in [0,1)
    return bi > (HBINS - 1) ? (HBINS - 1) : bi;
}

// meta per batch (16 u32):
// [4]=candcnt [8]=below [9..13]=win[5] [15]=stage_overflow

// ---- pass 0: zero meta ----
__global__ __launch_bounds__(256) void init_kernel(
    uint32_t* __restrict__ meta, int B) {
    const int i = blockIdx.x * 256 + threadIdx.x;
    if (i < B * 16) meta[i] = 0u;
}

// ---- pass 1: role-split stream dispatch ----
// [0, nG):        G role — count + gather candidates (64 blocks/batch)
// [nG, nG+nP):    P role — provisional masked output, 1 f4/thread
// [nG+nP, ...):   C role — src/tgt copy, 1 f4/thread
__global__ __launch_bounds__(256) void stream_kernel(
    const float4* __restrict__ cost4, const float4* __restrict__ src4,
    const float4* __restrict__ tgt4, float4* __restrict__ out4,
    float4* __restrict__ outc4, uint32_t* __restrict__ meta,
    uint32_t* __restrict__ candv, uint32_t* __restrict__ candi,
    int n4, int nG, int nP, int s4) {
    const int bid = blockIdx.x;
    const int tid = threadIdx.x;

    if (bid >= nG) {
        if (bid < nG + nP) {
            // ---- P role: provisional mask, 1 f4/thread, pure stream ----
            const size_t i = (size_t)(bid - nG) * 256 + tid;
            float4 v = cost4[i];
            float4 o;
            o.x = (costBin(v.x) <= SPEC_LO + 1) ? v.x : 0.0f;
            o.y = (costBin(v.y) <= SPEC_LO + 1) ? v.y : 0.0f;
            o.z = (costBin(v.z) <= SPEC_LO + 1) ? v.z : 0.0f;
            o.w = (costBin(v.w) <= SPEC_LO + 1) ? v.w : 0.0f;
            outc4[i] = o;
        } else {
            // ---- C role: src/tgt copy, 1 f4/thread, pure stream ----
            const int i = (bid - nG - nP) * 256 + tid;
            out4[i] = (i < s4) ? src4[i] : tgt4[i - s4];
        }
        return;
    }

    // ---- G role: count below/win + gather window candidates ----
    __shared__ uint32_t l_cv[LCAP];
    __shared__ uint32_t l_ci[LCAP];
    __shared__ uint32_t lh_win[5];
    __shared__ uint32_t l_below[4];
    __shared__ uint32_t l_cnt, l_base;
    const int b = bid >> 6;          // 64 G blocks per batch
    const int x = bid & 63;
    const int w = tid >> 6, ln = tid & 63;
    if (tid < 5) lh_win[tid] = 0;
    if (tid == 0) l_cnt = 0;
    __syncthreads();
    const size_t base4 = (size_t)b * n4 + (size_t)x * 4096;
    uint32_t below = 0;
    #pragma unroll
    for (int r = 0; r < 4; ++r) {
        const size_t r0 = base4 + (size_t)r * 1024;
        float4 v0 = cost4[r0 + 0 * 256 + tid];
        float4 v1 = cost4[r0 + 1 * 256 + tid];
        float4 v2 = cost4[r0 + 2 * 256 + tid];
        float4 v3 = cost4[r0 + 3 * 256 + tid];
        uint32_t bb[16];
        bb[0]  = costBin(v0.x); bb[1]  = costBin(v0.y); bb[2]  = costBin(v0.z); bb[3]  = costBin(v0.w);
        bb[4]  = costBin(v1.x); bb[5]  = costBin(v1.y); bb[6]  = costBin(v1.z); bb[7]  = costBin(v1.w);
        bb[8]  = costBin(v2.x); bb[9]  = costBin(v2.y); bb[10] = costBin(v2.z); bb[11] = costBin(v2.w);
        bb[12] = costBin(v3.x); bb[13] = costBin(v3.y); bb[14] = costBin(v3.z); bb[15] = costBin(v3.w);
        uint32_t hm = 0;
        #pragma unroll
        for (int k = 0; k < 16; ++k) {
            below += (bb[k] < SPEC_LO) ? 1u : 0u;
            hm |= ((uint32_t)(bb[k] >= SPEC_LO && bb[k] <= SPEC_HI)) << k;
        }
        if (hm) {
            const float vals[16] = {v0.x, v0.y, v0.z, v0.w, v1.x, v1.y, v1.z, v1.w,
                                    v2.x, v2.y, v2.z, v2.w, v3.x, v3.y, v3.z, v3.w};
            while (hm) {
                const int k = __ffs(hm) - 1;
                hm &= hm - 1;
                atomicAdd(&lh_win[bb[k] - SPEC_LO], 1u);
                const uint32_t p = atomicAdd(&l_cnt, 1u);
                if (p < (uint32_t)LCAP) {
                    l_cv[p] = __float_as_uint(vals[k]);
                    l_ci[p] = ((uint32_t)x * 4096u + (uint32_t)r * 1024u +
                               ((uint32_t)(k >> 2)) * 256u + (uint32_t)tid) * 4u +
                              (uint32_t)(k & 3);
                }
            }
        }
    }
    #pragma unroll
    for (int o = 1; o < 64; o <<= 1) below += (uint32_t)__shfl_xor((int)below, o);
    if (ln == 0) l_below[w] = below;
    __syncthreads();
    if (tid == 0)
        atomicAdd(&meta[b * 16 + 8],
                  l_below[0] + l_below[1] + l_below[2] + l_below[3]);
    if (tid < 5 && lh_win[tid])
        atomicAdd(&meta[b * 16 + 9 + tid], lh_win[tid]);
    const uint32_t tot = l_cnt;
    if (tid == 0 && tot > (uint32_t)LCAP) meta[b * 16 + 15] = 1u;  // -> miss
    const uint32_t n = (tot > (uint32_t)LCAP) ? (uint32_t)LCAP : tot;
    if (tid == 0) l_base = atomicAdd(&meta[b * 16 + 4], n);
    __syncthreads();
    uint32_t* cv = candv + (size_t)b * CAP;
    uint32_t* ci = candi + (size_t)b * CAP;
    const uint32_t gb = l_base;
    for (uint32_t i = tid; i < n; i += 256) {
        const uint32_t g = gb + i;
        if (g < (uint32_t)CAP) { cv[g] = l_cv[i]; ci[g] = l_ci[i]; }
    }
}

// ---- pass 2: validate + LDS-staged exact threshold/tie + output fixup ----
__global__ __launch_bounds__(NT) void solve_kernel(
    uint32_t* __restrict__ meta,
    uint32_t* __restrict__ candv, uint32_t* __restrict__ candi,
    const float4* __restrict__ cost4, float* __restrict__ outc,
    float4* __restrict__ outc4, int n4, uint32_t K, int N) {
    const int b = blockIdx.x;
    uint32_t* mb = meta + b * 16;
    const uint32_t* cv = candv + (size_t)b * CAP;
    const uint32_t* ci = candi + (size_t)b * CAP;
    __shared__ uint32_t scv[SCAP];
    __shared__ uint32_t sci[SCAP];
    __shared__ uint32_t hh[TIECAP];         // slow hist / descent / ties
    __shared__ uint32_t pref[HBINS];
    __shared__ uint32_t sw[4 * NW];
    __shared__ uint32_t s_q, s_lo, s_need, s_range, s_scnt, s_res;
    const int t = threadIdx.x;
    const int w = t >> 6, ln = t & 63;

    // -- validate speculation from below/win counts --
    const uint32_t below = mb[8];
    const uint32_t over = mb[15];
    const uint32_t c0r = mb[4];
    const uint32_t c0 = (c0r > (uint32_t)CAP) ? (uint32_t)CAP : c0r;
    uint32_t win[5];
    #pragma unroll
    for (int i = 0; i < 5; ++i) win[i] = mb[9 + i];
    int qrel = -1;
    {
        uint32_t cum = below;
        if (K <= cum) qrel = -1;
        else {
            qrel = 5;
            #pragma unroll
            for (int i = 0; i < 5; ++i) {
                if (K > cum && K <= cum + win[i]) { qrel = i; break; }
                cum += win[i];
            }
        }
    }
    const bool hit = (qrel >= 1 && qrel <= 3) && !over && (c0r <= (uint32_t)CAP);

    uint32_t need0;
    if (t == 0) s_scnt = 0;
    __syncthreads();

    if (hit) {
        // stage bins [q-1, q+1] from gathered candidates into LDS
        const uint32_t q = SPEC_LO + (uint32_t)qrel;
        uint32_t wb = 0;
        for (int i = 0; i < qrel - 1; ++i) wb += win[i];
        need0 = K - below - wb;
        for (uint32_t j = t; j < c0; j += NT) {
            const uint32_t v = cv[j];
            const uint32_t ix = ci[j];
            const uint32_t bi = costBin(__uint_as_float(v));
            const bool p = (bi + 1 >= q) && (bi <= q + 1);
            const uint64_t mk = __ballot(p);
            if (p) {
                const int leader = __ffsll((long long)mk) - 1;
                const uint32_t rank = (uint32_t)__popcll(mk & ((1ull << ln) - 1ull));
                uint32_t base = 0;
                if (ln == leader) base = atomicAdd(&s_scnt, (uint32_t)__popcll(mk));
                base = (uint32_t)__shfl((int)base, leader);
                const uint32_t pos = base + rank;
                if (pos < (uint32_t)SCAP) { scv[pos] = v; sci[pos] = ix; }
            }
        }
        __syncthreads();
    } else {
        // slow path (not taken for uniform data): full 512-bin hist,
        // locate crossing bin, stage [q-1, q+1] directly from cost
        for (int i = t; i < HBINS; i += NT) hh[i] = 0;
        __syncthreads();
        for (uint32_t i4 = (uint32_t)t; i4 < (uint32_t)n4; i4 += NT) {
            const float4 v = cost4[(size_t)b * n4 + i4];
            atomicAdd(&hh[costBin(v.x)], 1u);
            atomicAdd(&hh[costBin(v.y)], 1u);
            atomicAdd(&hh[costBin(v.z)], 1u);
            atomicAdd(&hh[costBin(v.w)], 1u);
        }
        __syncthreads();
        const uint32_t hv = hh[t];
        uint32_t incl = hv;
        #pragma unroll
        for (int o = 1; o < 64; o <<= 1) {
            const uint32_t u = (uint32_t)__shfl_up((int)incl, o);
            if (ln >= o) incl += u;
        }
        if (ln == 63) sw[w] = incl;
        if (t == 0) s_q = HBINS - 1;
        __syncthreads();
        uint32_t wbase = 0;
        for (int i = 0; i < w; ++i) wbase += sw[i];
        incl += wbase;
        pref[t] = incl;
        __syncthreads();
        if (K > incl - hv && K <= incl) s_q = (uint32_t)t;
        __syncthreads();
        const uint32_t q = s_q;
        const uint32_t lob = (q > 0) ? q - 1 : 0;
        const uint32_t hib = (q < HBINS - 1) ? q + 1 : (HBINS - 1);
        need0 = K - ((lob > 0) ? pref[lob - 1] : 0u);
        for (uint32_t i4 = (uint32_t)t; i4 < (uint32_t)n4; i4 += NT) {
            const float4 v = cost4[(size_t)b * n4 + i4];
            const float xx[4] = {v.x, v.y, v.z, v.w};
            #pragma unroll
            for (int j = 0; j < 4; ++j) {
                const uint32_t bi = costBin(xx[j]);
                const bool p = (bi >= lob && bi <= hib);
                const uint64_t mk = __ballot(p);
                if (p) {
                    const int leader = __ffsll((long long)mk) - 1;
                    const uint32_t rank = (uint32_t)__popcll(mk & ((1ull << ln) - 1ull));
                    uint32_t base = 0;
                    if (ln == leader) base = atomicAdd(&s_scnt, (uint32_t)__popcll(mk));
                    base = (uint32_t)__shfl((int)base, leader);
                    const uint32_t pos = base + rank;
                    if (pos < (uint32_t)SCAP) {
                        scv[pos] = __float_as_uint(xx[j]);
                        sci[pos] = i4 * 4u + (uint32_t)j;
                    }
                }
            }
        }
        __syncthreads();
    }
    // pathological overflow: clamp (same robustness class as prior rounds;
    // never triggered for this input distribution)
    const uint32_t scnt = (s_scnt > (uint32_t)SCAP) ? (uint32_t)SCAP : s_scnt;

    // -- block min/max of staged cost bits --
    uint32_t mn = 0xFFFFFFFFu, mx = 0u;
    for (uint32_t j = t; j < scnt; j += NT) {
        const uint32_t v = scv[j];
        mn = (v < mn) ? v : mn;
        mx = (v > mx) ? v : mx;
    }
    #pragma unroll
    for (int o = 1; o < 64; o <<= 1) {
        const uint32_t a = (uint32_t)__shfl_xor((int)mn, o);
        const uint32_t z = (uint32_t)__shfl_xor((int)mx, o);
        mn = (a < mn) ? a : mn;
        mx = (z > mx) ? z : mx;
    }
    if (ln == 0) { sw[w] = mn; sw[NW + w] = mx; }
    __syncthreads();
    uint32_t lo = sw[0], hix = sw[NW];
    #pragma unroll
    for (int i = 1; i < NW; ++i) {
        lo = (sw[i] < lo) ? sw[i] : lo;
        hix = (sw[NW + i] > hix) ? sw[NW + i] : hix;
    }
    uint32_t range = hix - lo + 1u;
    uint32_t need = need0;

    // -- histogram descent over LDS staged set --
    while (range > 1u) {
        const int bits = 32 - __clz((int)(range - 1u));
        const int shift = (bits > 11) ? (bits - 11) : 0;
        for (int i = t; i < TIECAP; i += NT) hh[i] = 0;
        __syncthreads();
        for (uint32_t j = t; j < scnt; j += NT) {
            const uint32_t v = scv[j];
            const uint32_t d = v - lo;
            if (v >= lo && d < range) atomicAdd(&hh[d >> shift], 1u);
        }
        __syncthreads();
        uint32_t hv4[4];
        uint32_t csum = 0;
        #pragma unroll
        for (int i = 0; i < 4; ++i) { hv4[i] = hh[t * 4 + i]; csum += hv4[i]; }
        uint32_t inc2 = csum;
        #pragma unroll
        for (int o = 1; o < 64; o <<= 1) {
            const uint32_t up = (uint32_t)__shfl_up((int)inc2, o);
            if (ln >= o) inc2 += up;
        }
        if (ln == 63) sw[w] = inc2;
        if (t == 0) { s_lo = lo; s_need = 1u; s_range = 1u; }
        __syncthreads();
        uint32_t wpre = 0;
        for (int i = 0; i < w; ++i) wpre += sw[i];
        const uint32_t before = wpre + inc2 - csum;
        if (before < need && before + csum >= need) {
            uint32_t cum = before;
            #pragma unroll
            for (int i = 0; i < 4; ++i) {
                if (cum + hv4[i] >= need) {
                    const uint32_t qq = (uint32_t)(t * 4 + i);
                    const uint32_t off = qq << shift;
                    s_lo = lo + off;
                    s_need = need - cum;
                    const uint32_t span = range - off;
                    s_range = (span < (1u << shift)) ? span : (1u << shift);
                    break;
                }
                cum += hv4[i];
            }
        }
        __syncthreads();
        lo = s_lo; need = s_need; range = s_range;
        __syncthreads();
    }
    const uint32_t thr = impBits(__uint_as_float(lo));

    // -- count gt/eq; min/max tie index (LDS only) --
    uint32_t cg = 0, ce = 0, imn = 0xFFFFFFFFu, imx = 0u;
    for (uint32_t j = t; j < scnt; j += NT) {
        const uint32_t ib = impBits(__uint_as_float(scv[j]));
        if (ib > thr) cg++;
        else if (ib == thr) {
            ce++;
            const uint32_t ix = sci[j];
            imn = (ix < imn) ? ix : imn;
            imx = (ix > imx) ? ix : imx;
        }
    }
    #pragma unroll
    for (int o = 1; o < 64; o <<= 1) {
        cg += (uint32_t)__shfl_xor((int)cg, o);
        ce += (uint32_t)__shfl_xor((int)ce, o);
        const uint32_t a = (uint32_t)__shfl_xor((int)imn, o);
        const uint32_t z = (uint32_t)__shfl_xor((int)imx, o);
        imn = (a < imn) ? a : imn;
        imx = (z > imx) ? z : imx;
    }
    if (ln == 0) { sw[w] = cg; sw[NW + w] = ce; sw[2 * NW + w] = imn; sw[3 * NW + w] = imx; }
    __syncthreads();
    uint32_t gt = 0, eq = 0, imin = 0xFFFFFFFFu, imax = 0u;
    #pragma unroll
    for (int i = 0; i < NW; ++i) {
        gt += sw[i];
        eq += sw[NW + i];
        imin = (sw[2 * NW + i] < imin) ? sw[2 * NW + i] : imin;
        imax = (sw[3 * NW + i] > imax) ? sw[3 * NW + i] : imax;
    }
    __syncthreads();

    const uint32_t m = need0 - gt;  // # threshold-equal elements to take
    uint32_t idxthr = 0xFFFFFFFFu;
    if (m < eq) {
        if (m == 1) {
            idxthr = imin;
        } else {
            // gather tie indices into hh, O(eq) rank-select
            if (t == 0) { s_scnt = 0; s_res = imin; }
            __syncthreads();
            for (uint32_t j = t; j < scnt; j += NT) {
                if (impBits(__uint_as_float(scv[j])) == thr) {
                    const uint32_t p = atomicAdd(&s_scnt, 1u);
                    if (p < (uint32_t)TIECAP) hh[p] = sci[j];
                }
            }
            __syncthreads();
            const uint32_t tc = s_scnt;
            if (tc <= (uint32_t)TIECAP) {
                for (uint32_t p = t; p < tc; p += NT) {
                    const uint32_t x = hh[p];
                    uint32_t r = 0;
                    for (uint32_t q2 = 0; q2 < tc; ++q2) r += (hh[q2] < x) ? 1u : 0u;
                    if (r == m - 1) s_res = x;
                }
                __syncthreads();
                idxthr = s_res;
            } else {
                // bsearch m-th smallest index over staged set
                uint32_t l2 = imin, h2 = imax;
                while (l2 < h2) {
                    const uint32_t mid = l2 + ((h2 - l2) >> 1);
                    uint32_t c = 0;
                    for (uint32_t j = t; j < scnt; j += NT)
                        c += (impBits(__uint_as_float(scv[j])) == thr && sci[j] <= mid) ? 1u : 0u;
                    #pragma unroll
                    for (int o = 1; o < 64; o <<= 1) c += (uint32_t)__shfl_xor((int)c, o);
                    if (ln == 0) sw[w] = c;
                    __syncthreads();
                    uint32_t tot2 = 0;
                    for (int i = 0; i < NW; ++i) tot2 += sw[i];
                    __syncthreads();
                    if (tot2 >= m) h2 = mid; else l2 = mid + 1;
                }
                idxthr = l2;
            }
        }
    }

    // -- output fixup (thr, idxthr block-uniform) --
    if (hit) {
        // scatter definitive values for staged candidates only
        float* ob = outc + (size_t)b * N;
        for (uint32_t j = t; j < scnt; j += NT) {
            const uint32_t vbits = scv[j];
            const uint32_t ix = sci[j];
            const uint32_t ib = impBits(__uint_as_float(vbits));
            const bool keep = (ib > thr) || (ib == thr && ix <= idxthr);
            ob[ix] = keep ? __uint_as_float(vbits) : 0.0f;
        }
    } else {
        // full re-mask of this batch (slow, correctness-only)
        const float4* cc4 = cost4 + (size_t)b * n4;
        float4* oc4 = outc4 + (size_t)b * n4;
        for (uint32_t i4 = (uint32_t)t; i4 < (uint32_t)n4; i4 += NT) {
            float4 v = cc4[i4];
            const uint32_t e0 = i4 * 4u;
            float4 o;
            uint32_t bx;
            bx = impBits(v.x); o.x = (bx > thr || (bx == thr && e0 + 0 <= idxthr)) ? v.x : 0.0f;
            bx = impBits(v.y); o.y = (bx > thr || (bx == thr && e0 + 1 <= idxthr)) ? v.y : 0.0f;
            bx = impBits(v.z); o.z = (bx > thr || (bx == thr && e0 + 2 <= idxthr)) ? v.z : 0.0f;
            bx = impBits(v.w); o.w = (bx > thr || (bx == thr && e0 + 3 <= idxthr)) ? v.w : 0.0f;
            oc4[i4] = o;
        }
    }
}

extern "C" void kernel_launch(void* const* d_in, const int* in_sizes, int n_in,
                              void* d_out, int out_size, void* d_ws, size_t ws_size,
                              hipStream_t stream) {
    const float* src  = (const float*)d_in[0];
    const float* tgt  = (const float*)d_in[1];
    const float* cost = (const float*)d_in[2];
    const int srcN = in_sizes[0];
    const int tgtN = in_sizes[1];
    const int costN = in_sizes[2];
    const int S = 1024, T = 1024;
    const int N = S * T;
    const int B = costN / N;
    const uint32_t K = (uint32_t)(((uint64_t)N * 2ull) / 10ull);  // int(N*0.2)

    float* out = (float*)d_out;

    uint32_t* meta  = (uint32_t*)d_ws;
    uint32_t* candv = meta + (size_t)B * 16;
    uint32_t* candi = candv + (size_t)B * CAP;

    const int n4 = N / 4;               // 262144 = 2^18
    const int s4 = srcN / 4, t4 = tgtN / 4;
    const int nG = B * 64;              // gather blocks (4096 f4 each)
    const int nP = (B * n4) / 256;      // provisional blocks (1 f4/thread)
    const int nC = (s4 + t4) / 256;     // copy blocks (1 f4/thread)

    float* outc = out + (size_t)srcN + tgtN;

    dim3 blk(256, 1, 1);

    init_kernel<<<(B * 16 + 255) / 256, blk, 0, stream>>>(meta, B);
    stream_kernel<<<nG + nP + nC, blk, 0, stream>>>(
        (const float4*)cost, (const float4*)src, (const float4*)tgt,
        (float4*)out, (float4*)outc, meta, candv, candi, n4, nG, nP, s4);
    solve_kernel<<<B, NT, 0, stream>>>(meta, candv, candi,
                                       (const float4*)cost, outc,
                                       (float4*)outc, n4, K, N);
}